// Round 1
// baseline (5364.694 us; speedup 1.0000x reference)
//
#include <hip/hip_runtime.h>
#include <hip/hip_bf16.h>

constexpr int kN = 4096;
constexpr int kDim = 66;   // U + IN
constexpr int kPDim = 68;  // padded to 17*float4
constexpr int kH = 4;
constexpr int kHD = 264;   // H*DIM
constexpr int kU = 64;
constexpr float kAlpha = 0.2f;
constexpr float kSlope = 0.01f;

// ---------- adjacency bit-pack: 67 MB int32 -> 2 MB bitmask ----------
__global__ void pack_adj_k(const int* __restrict__ adj, unsigned long long* __restrict__ packed){
  int gid = blockIdx.x * 256 + threadIdx.x;
  unsigned long long m = __ballot(adj[gid] != 0);
  if ((threadIdx.x & 63) == 0) packed[gid >> 6] = m;
}

// ---------- x1 = concat(inputs, hx) ----------
__global__ void build_x1_k(const float* __restrict__ in2, const float* __restrict__ hx, float* __restrict__ x){
  int i = blockIdx.x, t = threadIdx.x; // 64 threads
  if (t < 2) x[i * kDim + t] = in2[i * 2 + t];
  x[i * kDim + 2 + t] = hx[i * kU + t];
}

// ---------- per-head h = x@W (66x66), f1=h@a1, f2=h@a2 ----------
__global__ void head_transform_k(const float* __restrict__ x, const float* __restrict__ W,
                                 const float* __restrict__ a1, const float* __restrict__ a2,
                                 float* __restrict__ h, float* __restrict__ f1, float* __restrict__ f2){
  int i = blockIdx.x, m = blockIdx.y, t = threadIdx.x; // 64 threads
  __shared__ float xs[kDim];
  if (t < 2) xs[t] = x[i * kDim + t];
  xs[2 + t] = x[i * kDim + 2 + t];
  __syncthreads();
  const float* Wm = W + (size_t)m * kDim * kDim;
  float acc0 = 0.f, acc1 = 0.f;
  for (int k = 0; k < kDim; k++){
    float xv = xs[k];
    acc0 += xv * Wm[k * kDim + t];
    if (t < 2) acc1 += xv * Wm[k * kDim + 64 + t];
  }
  float* hrow = h + (size_t)(m * kN + i) * kPDim;
  hrow[t] = acc0;
  if (t < 2) hrow[64 + t] = acc1;
  if (t >= 2 && t < 4) hrow[64 + t] = 0.f; // zero pad cols 66,67
  const float* a1m = a1 + m * kDim;
  const float* a2m = a2 + m * kDim;
  float p1 = acc0 * a1m[t], p2 = acc0 * a2m[t];
  if (t < 2){ p1 += acc1 * a1m[64 + t]; p2 += acc1 * a2m[64 + t]; }
  #pragma unroll
  for (int o = 32; o; o >>= 1){ p1 += __shfl_down(p1, o); p2 += __shfl_down(p2, o); }
  if (t == 0){ f1[m * kN + i] = p1; f2[m * kN + i] = p2; }
}

// ---------- out-layer h = lrelu(hcat)@Wout (264x66), fo1, fo2 ----------
__global__ void out_transform_k(const float* __restrict__ hcat, const float* __restrict__ Wout,
                                const float* __restrict__ ao1, const float* __restrict__ ao2,
                                float* __restrict__ hh, float* __restrict__ fo1, float* __restrict__ fo2){
  int i = blockIdx.x, t = threadIdx.x; // 64 threads
  __shared__ float xs[kHD];
  for (int k = t; k < kHD; k += 64) xs[k] = hcat[(size_t)i * kHD + k];
  __syncthreads();
  float acc0 = 0.f, acc1 = 0.f;
  for (int k = 0; k < kHD; k++){
    float xv = xs[k];
    acc0 += xv * Wout[k * kDim + t];
    if (t < 2) acc1 += xv * Wout[k * kDim + 64 + t];
  }
  float* hrow = hh + (size_t)i * kPDim;
  hrow[t] = acc0;
  if (t < 2) hrow[64 + t] = acc1;
  if (t >= 2 && t < 4) hrow[64 + t] = 0.f;
  float p1 = acc0 * ao1[t], p2 = acc0 * ao2[t];
  if (t < 2){ p1 += acc1 * ao1[64 + t]; p2 += acc1 * ao2[64 + t]; }
  #pragma unroll
  for (int o = 32; o; o >>= 1){ p1 += __shfl_down(p1, o); p2 += __shfl_down(p2, o); }
  if (t == 0){ fo1[i] = p1; fo2[i] = p2; }
}

// ---------- max over f2 per array (for safe fixed softmax shift) ----------
__global__ void reduce_max_k(const float* __restrict__ f2, float* __restrict__ fmax){
  int m = blockIdx.x;
  const float* p = f2 + (size_t)m * kN;
  float v = -1e30f;
  for (int j = threadIdx.x; j < kN; j += 256) v = fmaxf(v, p[j]);
  #pragma unroll
  for (int o = 32; o; o >>= 1) v = fmaxf(v, __shfl_down(v, o));
  __shared__ float s[4];
  if ((threadIdx.x & 63) == 0) s[threadIdx.x >> 6] = v;
  __syncthreads();
  if (threadIdx.x == 0) fmax[m] = fmaxf(fmaxf(s[0], s[1]), fmaxf(s[2], s[3]));
}

// ---------- masked-softmax attention: out_i = lrelu( softmax_j(e_ij) @ h , 0.01 ) ----------
// thread-per-row, 64-col h chunks staged in LDS (broadcast reads), fixed shift S_i.
__global__ __launch_bounds__(256) void gat_attn_k(
    const float* __restrict__ hsrc, const float* __restrict__ f1,
    const float* __restrict__ f2, const float* __restrict__ fmax,
    const unsigned long long* __restrict__ packed,
    float* __restrict__ out, int out_stride)
{
  int m = blockIdx.y;
  int i = blockIdx.x * 256 + threadIdx.x;
  const float* hm = hsrc + (size_t)m * kN * kPDim;
  const float* f2m = f2 + (size_t)m * kN;
  float fi = f1[(size_t)m * kN + i];
  float t0 = fi + fmax[m];
  float S = fmaxf(t0, kAlpha * t0); // lrelu(t0) >= row max of e
  float4 acc[17];
  #pragma unroll
  for (int q = 0; q < 17; q++) acc[q] = make_float4(0.f, 0.f, 0.f, 0.f);
  float l = 0.f;
  __shared__ float4 hs4[64 * 17];
  __shared__ float f2s[64];
  const unsigned long long* prow = packed + (size_t)i * 64;
  for (int c = 0; c < 64; c++){
    __syncthreads();
    const float4* src4 = (const float4*)(hm + (size_t)c * 64 * kPDim);
    for (int t = threadIdx.x; t < 64 * 17; t += 256) hs4[t] = src4[t];
    if (threadIdx.x < 64) f2s[threadIdx.x] = f2m[c * 64 + threadIdx.x];
    __syncthreads();
    unsigned long long bits = prow[c];
    #pragma unroll 2
    for (int j = 0; j < 64; j++){
      float tt = fi + f2s[j];
      float e = fmaxf(tt, kAlpha * tt);
      float p = __expf(e - S);
      p = ((bits >> j) & 1ull) ? p : 0.f;
      l += p;
      const float4* hj = hs4 + j * 17;
      #pragma unroll
      for (int q = 0; q < 17; q++){
        float4 hv = hj[q];
        acc[q].x += p * hv.x; acc[q].y += p * hv.y;
        acc[q].z += p * hv.z; acc[q].w += p * hv.w;
      }
    }
  }
  float inv = 1.f / l;
  float av[68];
  #pragma unroll
  for (int q = 0; q < 17; q++) ((float4*)av)[q] = acc[q];
  float* orow = out + (size_t)i * out_stride + m * kDim;
  #pragma unroll
  for (int d = 0; d < kDim; d++){
    float v = av[d] * inv;
    orow[d] = fmaxf(v, kSlope * v); // lrelu 0.01 (hcat activation / subnet output)
  }
}

// ---------- value = sigmoid(g1@g1W+b); u saved; x2 = concat(xi, r*hx) ----------
__global__ void gating_k(const float* __restrict__ g1, const float* __restrict__ g1W, const float* __restrict__ g1b,
                         const float* __restrict__ in2, const float* __restrict__ hx,
                         float* __restrict__ u, float* __restrict__ x2){
  int i = blockIdx.x, t = threadIdx.x; // 128 threads
  __shared__ float gs[kDim];
  if (t < kDim) gs[t] = g1[(size_t)i * kDim + t];
  __syncthreads();
  float acc = g1b[t];
  for (int k = 0; k < kDim; k++) acc += gs[k] * g1W[k * 128 + t];
  float v = 1.f / (1.f + __expf(-acc));
  if (t < 64){
    x2[(size_t)i * kDim + 2 + t] = v * hx[(size_t)i * kU + t]; // r * hx
  } else {
    u[(size_t)i * kU + (t - 64)] = v;
  }
  if (t < 2) x2[(size_t)i * kDim + t] = in2[i * 2 + t];
}

// ---------- c = tanh(g2@g2W+b); out = u*hx + (1-u)*c ----------
__global__ void final_k(const float* __restrict__ g2, const float* __restrict__ g2W, const float* __restrict__ g2b,
                        const float* __restrict__ u, const float* __restrict__ hx, float* __restrict__ out){
  int i = blockIdx.x, t = threadIdx.x; // 64 threads
  __shared__ float gs[kDim];
  gs[t] = g2[(size_t)i * kDim + t];
  if (t < 2) gs[64 + t] = g2[(size_t)i * kDim + 64 + t];
  __syncthreads();
  float acc = g2b[t];
  for (int k = 0; k < kDim; k++) acc += gs[k] * g2W[k * kU + t];
  float c = tanhf(acc);
  float uv = u[(size_t)i * kU + t];
  out[(size_t)i * kU + t] = uv * hx[(size_t)i * kU + t] + (1.f - uv) * c;
}

extern "C" void kernel_launch(void* const* d_in, const int* in_sizes, int n_in,
                              void* d_out, int out_size, void* d_ws, size_t ws_size,
                              hipStream_t stream){
  const float* inputs  = (const float*)d_in[0];
  const float* hx      = (const float*)d_in[1];
  const int*   adj     = (const int*)d_in[2];
  const float* m1_W    = (const float*)d_in[3];
  const float* m1_a1   = (const float*)d_in[4];
  const float* m1_a2   = (const float*)d_in[5];
  const float* m1_Wout = (const float*)d_in[6];
  const float* m1_ao1  = (const float*)d_in[7];
  const float* m1_ao2  = (const float*)d_in[8];
  const float* m2_W    = (const float*)d_in[9];
  const float* m2_a1   = (const float*)d_in[10];
  const float* m2_a2   = (const float*)d_in[11];
  const float* m2_Wout = (const float*)d_in[12];
  const float* m2_ao1  = (const float*)d_in[13];
  const float* m2_ao2  = (const float*)d_in[14];
  const float* g1_W    = (const float*)d_in[15];
  const float* g1_b    = (const float*)d_in[16];
  const float* g2_W    = (const float*)d_in[17];
  const float* g2_b    = (const float*)d_in[18];
  float* out = (float*)d_out;

  char* ws = (char*)d_ws;
  size_t off = 0;
  auto alloc = [&](size_t bytes) -> void* {
    void* p = ws + off;
    off = (off + bytes + 255) & ~(size_t)255;
    return p;
  };
  unsigned long long* packed = (unsigned long long*)alloc((size_t)kN * 64 * 8); // 2 MB
  float* x    = (float*)alloc((size_t)kN * kDim * 4);
  float* h    = (float*)alloc((size_t)kH * kN * kPDim * 4);
  float* f1   = (float*)alloc((size_t)kH * kN * 4);
  float* f2   = (float*)alloc((size_t)kH * kN * 4);
  float* fmax = (float*)alloc(64);
  float* hcat = (float*)alloc((size_t)kN * kHD * 4);
  float* hh   = (float*)alloc((size_t)kN * kPDim * 4);
  float* fo1  = (float*)alloc((size_t)kN * 4);
  float* fo2  = (float*)alloc((size_t)kN * 4);
  float* g    = (float*)alloc((size_t)kN * kDim * 4);
  float* u    = (float*)alloc((size_t)kN * kU * 4);
  float* x2   = (float*)alloc((size_t)kN * kDim * 4);
  (void)ws_size; (void)in_sizes; (void)n_in; (void)out_size;

  pack_adj_k<<<kN * kN / 256, 256, 0, stream>>>(adj, packed);
  build_x1_k<<<kN, 64, 0, stream>>>(inputs, hx, x);

  // ---- subnet 1 ----
  head_transform_k<<<dim3(kN, kH), 64, 0, stream>>>(x, m1_W, m1_a1, m1_a2, h, f1, f2);
  reduce_max_k<<<kH, 256, 0, stream>>>(f2, fmax);
  gat_attn_k<<<dim3(16, kH), 256, 0, stream>>>(h, f1, f2, fmax, packed, hcat, kHD);
  out_transform_k<<<kN, 64, 0, stream>>>(hcat, m1_Wout, m1_ao1, m1_ao2, hh, fo1, fo2);
  reduce_max_k<<<1, 256, 0, stream>>>(fo2, fmax + 4);
  gat_attn_k<<<dim3(16, 1), 256, 0, stream>>>(hh, fo1, fo2, fmax + 4, packed, g, kDim);
  gating_k<<<kN, 128, 0, stream>>>(g, g1_W, g1_b, inputs, hx, u, x2);

  // ---- subnet 2 ----
  head_transform_k<<<dim3(kN, kH), 64, 0, stream>>>(x2, m2_W, m2_a1, m2_a2, h, f1, f2);
  reduce_max_k<<<kH, 256, 0, stream>>>(f2, fmax);
  gat_attn_k<<<dim3(16, kH), 256, 0, stream>>>(h, f1, f2, fmax, packed, hcat, kHD);
  out_transform_k<<<kN, 64, 0, stream>>>(hcat, m2_Wout, m2_ao1, m2_ao2, hh, fo1, fo2);
  reduce_max_k<<<1, 256, 0, stream>>>(fo2, fmax + 4);
  gat_attn_k<<<dim3(16, 1), 256, 0, stream>>>(hh, fo1, fo2, fmax + 4, packed, g, kDim);
  final_k<<<kN, 64, 0, stream>>>(g, g2_W, g2_b, u, hx, out);
}

// Round 2
// 561.813 us; speedup vs baseline: 9.5489x; 9.5489x over previous
//
#include <hip/hip_runtime.h>
#include <hip/hip_bf16.h>

constexpr int kN = 4096;
constexpr int kDim = 66;   // U + IN
constexpr int kH = 4;
constexpr int kHD = 264;   // H*DIM
constexpr int kU = 64;
constexpr float kAlpha = 0.2f;
constexpr float kSlope = 0.01f;

typedef __attribute__((ext_vector_type(8))) short short8;
typedef __attribute__((ext_vector_type(4))) float floatx4;

__device__ inline unsigned short f2bf(float x){
  unsigned int u = __float_as_uint(x);
  unsigned int r = (u + 0x7FFFu + ((u >> 16) & 1u)) >> 16; // RNE
  return (unsigned short)r;
}

// ---------- adjacency bit-pack: 67 MB int32 -> 2 MB bitmask ----------
__global__ void pack_adj_k(const int* __restrict__ adj, unsigned long long* __restrict__ packed){
  int gid = blockIdx.x * 256 + threadIdx.x;
  unsigned long long m = __ballot(adj[gid] != 0);
  if ((threadIdx.x & 63) == 0) packed[gid >> 6] = m;
}

// ---------- x1 = concat(inputs, hx) ----------
__global__ void build_x1_k(const float* __restrict__ in2, const float* __restrict__ hx, float* __restrict__ x){
  int i = blockIdx.x, t = threadIdx.x; // 64 threads
  if (t < 2) x[i * kDim + t] = in2[i * 2 + t];
  x[i * kDim + 2 + t] = hx[i * kU + t];
}

// ---------- per-head: h=x@W, write Ht (bf16, transposed, 80 rows: 66 h + ones + zeros), f1, f2 ----------
__global__ void head_transform_k(const float* __restrict__ x, const float* __restrict__ W,
                                 const float* __restrict__ a1, const float* __restrict__ a2,
                                 unsigned short* __restrict__ Ht, float* __restrict__ f1, float* __restrict__ f2){
  int i = blockIdx.x, m = blockIdx.y, t = threadIdx.x; // 64 threads
  __shared__ float xs[kDim];
  if (t < 2) xs[t] = x[i * kDim + t];
  xs[2 + t] = x[i * kDim + 2 + t];
  __syncthreads();
  const float* Wm = W + (size_t)m * kDim * kDim;
  float acc0 = 0.f, acc1 = 0.f;
  for (int k = 0; k < kDim; k++){
    float xv = xs[k];
    acc0 += xv * Wm[k * kDim + t];
    if (t < 2) acc1 += xv * Wm[k * kDim + 64 + t];
  }
  unsigned short* Hm = Ht + (size_t)m * 80 * kN;
  Hm[(size_t)t * kN + i] = f2bf(acc0);
  if (t < 2)            Hm[(size_t)(64 + t) * kN + i] = f2bf(acc1);
  if (t == 2)           Hm[(size_t)66 * kN + i] = 0x3F80;       // ones column -> row-sum l_i
  if (t >= 3 && t < 16) Hm[(size_t)(64 + t) * kN + i] = 0;      // cols 67..79 zero
  const float* a1m = a1 + m * kDim;
  const float* a2m = a2 + m * kDim;
  float p1 = acc0 * a1m[t], p2 = acc0 * a2m[t];
  if (t < 2){ p1 += acc1 * a1m[64 + t]; p2 += acc1 * a2m[64 + t]; }
  #pragma unroll
  for (int o = 32; o; o >>= 1){ p1 += __shfl_down(p1, o); p2 += __shfl_down(p2, o); }
  if (t == 0){ f1[m * kN + i] = p1; f2[m * kN + i] = p2; }
}

// ---------- out-layer: h=hcat@Wout, write Hto (bf16 transposed + ones), fo1, fo2 ----------
__global__ void out_transform_k(const float* __restrict__ hcat, const float* __restrict__ Wout,
                                const float* __restrict__ ao1, const float* __restrict__ ao2,
                                unsigned short* __restrict__ Hto, float* __restrict__ fo1, float* __restrict__ fo2){
  int i = blockIdx.x, t = threadIdx.x; // 64 threads
  __shared__ float xs[kHD];
  for (int k = t; k < kHD; k += 64) xs[k] = hcat[(size_t)i * kHD + k];
  __syncthreads();
  float acc0 = 0.f, acc1 = 0.f;
  for (int k = 0; k < kHD; k++){
    float xv = xs[k];
    acc0 += xv * Wout[k * kDim + t];
    if (t < 2) acc1 += xv * Wout[k * kDim + 64 + t];
  }
  Hto[(size_t)t * kN + i] = f2bf(acc0);
  if (t < 2)            Hto[(size_t)(64 + t) * kN + i] = f2bf(acc1);
  if (t == 2)           Hto[(size_t)66 * kN + i] = 0x3F80;
  if (t >= 3 && t < 16) Hto[(size_t)(64 + t) * kN + i] = 0;
  float p1 = acc0 * ao1[t], p2 = acc0 * ao2[t];
  if (t < 2){ p1 += acc1 * ao1[64 + t]; p2 += acc1 * ao2[64 + t]; }
  #pragma unroll
  for (int o = 32; o; o >>= 1){ p1 += __shfl_down(p1, o); p2 += __shfl_down(p2, o); }
  if (t == 0){ fo1[i] = p1; fo2[i] = p2; }
}

// ---------- max over f2 per array (safe fixed softmax shift) ----------
__global__ void reduce_max_k(const float* __restrict__ f2, float* __restrict__ fmax){
  int m = blockIdx.x;
  const float* p = f2 + (size_t)m * kN;
  float v = -1e30f;
  for (int j = threadIdx.x; j < kN; j += 256) v = fmaxf(v, p[j]);
  #pragma unroll
  for (int o = 32; o; o >>= 1) v = fmaxf(v, __shfl_down(v, o));
  __shared__ float s[4];
  if ((threadIdx.x & 63) == 0) s[threadIdx.x >> 6] = v;
  __syncthreads();
  if (threadIdx.x == 0) fmax[m] = fmaxf(fmaxf(s[0], s[1]), fmaxf(s[2], s[3]));
}

// ---------- MFMA attention: pacc[m,js][i][0..79] = sum_j p_ij * Ht[j][col]  (col 66 = l_i) ----------
// P computed in-register in A-fragment layout; Ht chunk staged in LDS, B-frags via ds_read_b128.
__global__ __launch_bounds__(256, 4) void attn_mfma_k(
    const unsigned short* __restrict__ Ht, const float* __restrict__ f1,
    const float* __restrict__ f2, const float* __restrict__ fmax,
    const unsigned long long* __restrict__ packed,
    float* __restrict__ pacc)
{
  const int m = blockIdx.y, js = blockIdx.z;
  const int i0 = blockIdx.x * 64;
  const int t = threadIdx.x;
  const int w = t >> 6, lane = t & 63, q = lane >> 4, n = lane & 15;
  const int i = i0 + w * 16 + n;            // A-operand row for this lane
  const unsigned short* Hg = Ht + (size_t)m * 80 * kN;
  const float* f2m = f2 + (size_t)m * kN;
  const float f1v = f1[(size_t)m * kN + i];
  const float t0 = f1v + fmax[m];
  const float S = fmaxf(t0, kAlpha * t0);    // lrelu(t0) >= row max of e

  __shared__ __align__(16) unsigned short HtL[80 * 136]; // 128 + 8 pad per row
  __shared__ __align__(16) float f2s[128];

  floatx4 acc[5];
  #pragma unroll
  for (int v = 0; v < 5; v++) acc[v] = (floatx4){0.f, 0.f, 0.f, 0.f};

  const int jbase = js * 1024;
  for (int ch = 0; ch < 8; ch++){
    const int j0 = jbase + ch * 128;
    __syncthreads();
    for (int z = t; z < 80 * 16; z += 256){
      int row = z >> 4, c16 = z & 15;
      *(uint4*)&HtL[row * 136 + c16 * 8] = *(const uint4*)&Hg[(size_t)row * kN + j0 + c16 * 8];
    }
    if (t < 128) f2s[t] = f2m[j0 + t];
    __syncthreads();
    unsigned long long w0 = packed[(size_t)i * 64 + (j0 >> 6)];
    unsigned long long w1 = packed[(size_t)i * 64 + (j0 >> 6) + 1];
    #pragma unroll
    for (int ks = 0; ks < 4; ks++){
      unsigned long long wsel = (ks < 2) ? w0 : w1;
      unsigned int bits = (unsigned int)((wsel >> ((ks & 1) * 32 + q * 8)) & 0xffull);
      const float* fp = &f2s[ks * 32 + q * 8];
      short8 af;
      #pragma unroll
      for (int e = 0; e < 8; e++){
        float tt = f1v + fp[e];
        float ee = fmaxf(tt, kAlpha * tt);
        float p = __expf(ee - S);
        p = ((bits >> e) & 1u) ? p : 0.f;
        af[e] = (short)f2bf(p);
      }
      #pragma unroll
      for (int nt = 0; nt < 5; nt++){
        const short8 bf = *(const short8*)&HtL[(nt * 16 + n) * 136 + ks * 32 + q * 8];
        acc[nt] = __builtin_amdgcn_mfma_f32_16x16x32_bf16(af, bf, acc[nt], 0, 0, 0);
      }
    }
  }
  float* pw = pacc + ((size_t)(m * 4 + js) * kN + (i0 + w * 16)) * 80;
  #pragma unroll
  for (int nt = 0; nt < 5; nt++){
    #pragma unroll
    for (int r = 0; r < 4; r++)
      pw[(q * 4 + r) * 80 + nt * 16 + n] = acc[nt][r];  // D: col=lane&15, row=q*4+reg
  }
}

// ---------- combine j-split partials: out = lrelu( sum_js acc / sum_js l ) ----------
__global__ void combine_k(const float* __restrict__ pacc, float* __restrict__ out, int out_stride){
  int m = blockIdx.y;
  int i = blockIdx.x * 64 + (threadIdx.x >> 2);
  int cg = threadIdx.x & 3;
  const float* p0 = pacc + ((size_t)(m * 4 + 0) * kN + i) * 80;
  const float* p1 = p0 + (size_t)kN * 80;
  const float* p2 = p1 + (size_t)kN * 80;
  const float* p3 = p2 + (size_t)kN * 80;
  float l = p0[66] + p1[66] + p2[66] + p3[66];
  float inv = 1.f / l;
  float* orow = out + (size_t)i * out_stride + m * kDim;
  #pragma unroll
  for (int cc = 0; cc < 17; cc++){
    int c = cg * 17 + cc;
    if (c < kDim){
      float v = (p0[c] + p1[c] + p2[c] + p3[c]) * inv;
      orow[c] = fmaxf(v, kSlope * v);
    }
  }
}

// ---------- value = sigmoid(g1@g1W+b); u saved; x2 = concat(xi, r*hx) ----------
__global__ void gating_k(const float* __restrict__ g1, const float* __restrict__ g1W, const float* __restrict__ g1b,
                         const float* __restrict__ in2, const float* __restrict__ hx,
                         float* __restrict__ u, float* __restrict__ x2){
  int i = blockIdx.x, t = threadIdx.x; // 128 threads
  __shared__ float gs[kDim];
  if (t < kDim) gs[t] = g1[(size_t)i * kDim + t];
  __syncthreads();
  float acc = g1b[t];
  for (int k = 0; k < kDim; k++) acc += gs[k] * g1W[k * 128 + t];
  float v = 1.f / (1.f + __expf(-acc));
  if (t < 64){
    x2[(size_t)i * kDim + 2 + t] = v * hx[(size_t)i * kU + t]; // r * hx
  } else {
    u[(size_t)i * kU + (t - 64)] = v;
  }
  if (t < 2) x2[(size_t)i * kDim + t] = in2[i * 2 + t];
}

// ---------- c = tanh(g2@g2W+b); out = u*hx + (1-u)*c ----------
__global__ void final_k(const float* __restrict__ g2, const float* __restrict__ g2W, const float* __restrict__ g2b,
                        const float* __restrict__ u, const float* __restrict__ hx, float* __restrict__ out){
  int i = blockIdx.x, t = threadIdx.x; // 64 threads
  __shared__ float gs[kDim];
  gs[t] = g2[(size_t)i * kDim + t];
  if (t < 2) gs[64 + t] = g2[(size_t)i * kDim + 64 + t];
  __syncthreads();
  float acc = g2b[t];
  for (int k = 0; k < kDim; k++) acc += gs[k] * g2W[k * kU + t];
  float c = tanhf(acc);
  float uv = u[(size_t)i * kU + t];
  out[(size_t)i * kU + t] = uv * hx[(size_t)i * kU + t] + (1.f - uv) * c;
}

extern "C" void kernel_launch(void* const* d_in, const int* in_sizes, int n_in,
                              void* d_out, int out_size, void* d_ws, size_t ws_size,
                              hipStream_t stream){
  const float* inputs  = (const float*)d_in[0];
  const float* hx      = (const float*)d_in[1];
  const int*   adj     = (const int*)d_in[2];
  const float* m1_W    = (const float*)d_in[3];
  const float* m1_a1   = (const float*)d_in[4];
  const float* m1_a2   = (const float*)d_in[5];
  const float* m1_Wout = (const float*)d_in[6];
  const float* m1_ao1  = (const float*)d_in[7];
  const float* m1_ao2  = (const float*)d_in[8];
  const float* m2_W    = (const float*)d_in[9];
  const float* m2_a1   = (const float*)d_in[10];
  const float* m2_a2   = (const float*)d_in[11];
  const float* m2_Wout = (const float*)d_in[12];
  const float* m2_ao1  = (const float*)d_in[13];
  const float* m2_ao2  = (const float*)d_in[14];
  const float* g1_W    = (const float*)d_in[15];
  const float* g1_b    = (const float*)d_in[16];
  const float* g2_W    = (const float*)d_in[17];
  const float* g2_b    = (const float*)d_in[18];
  float* out = (float*)d_out;

  char* ws = (char*)d_ws;
  size_t off = 0;
  auto alloc = [&](size_t bytes) -> void* {
    void* p = ws + off;
    off = (off + bytes + 255) & ~(size_t)255;
    return p;
  };
  unsigned long long* packed = (unsigned long long*)alloc((size_t)kN * 64 * 8); // 2 MB
  float* x    = (float*)alloc((size_t)kN * kDim * 4);
  unsigned short* Ht  = (unsigned short*)alloc((size_t)kH * 80 * kN * 2); // 2.6 MB
  unsigned short* Hto = (unsigned short*)alloc((size_t)80 * kN * 2);
  float* f1   = (float*)alloc((size_t)kH * kN * 4);
  float* f2   = (float*)alloc((size_t)kH * kN * 4);
  float* fo1  = (float*)alloc((size_t)kN * 4);
  float* fo2  = (float*)alloc((size_t)kN * 4);
  float* fmax = (float*)alloc(64);
  float* hcat = (float*)alloc((size_t)kN * kHD * 4);
  float* g    = (float*)alloc((size_t)kN * kDim * 4);
  float* u    = (float*)alloc((size_t)kN * kU * 4);
  float* x2   = (float*)alloc((size_t)kN * kDim * 4);
  float* pacc = (float*)alloc((size_t)16 * kN * 80 * 4); // 21 MB (4 heads x 4 j-splits)
  (void)ws_size; (void)in_sizes; (void)n_in; (void)out_size;

  pack_adj_k<<<kN * kN / 256, 256, 0, stream>>>(adj, packed);
  build_x1_k<<<kN, 64, 0, stream>>>(inputs, hx, x);

  // ---- subnet 1 ----
  head_transform_k<<<dim3(kN, kH), 64, 0, stream>>>(x, m1_W, m1_a1, m1_a2, Ht, f1, f2);
  reduce_max_k<<<kH, 256, 0, stream>>>(f2, fmax);
  attn_mfma_k<<<dim3(64, kH, 4), 256, 0, stream>>>(Ht, f1, f2, fmax, packed, pacc);
  combine_k<<<dim3(64, kH), 256, 0, stream>>>(pacc, hcat, kHD);
  out_transform_k<<<kN, 64, 0, stream>>>(hcat, m1_Wout, m1_ao1, m1_ao2, Hto, fo1, fo2);
  reduce_max_k<<<1, 256, 0, stream>>>(fo2, fmax + 4);
  attn_mfma_k<<<dim3(64, 1, 4), 256, 0, stream>>>(Hto, fo1, fo2, fmax + 4, packed, pacc);
  combine_k<<<dim3(64, 1), 256, 0, stream>>>(pacc, g, kDim);
  gating_k<<<kN, 128, 0, stream>>>(g, g1_W, g1_b, inputs, hx, u, x2);

  // ---- subnet 2 ----
  head_transform_k<<<dim3(kN, kH), 64, 0, stream>>>(x2, m2_W, m2_a1, m2_a2, Ht, f1, f2);
  reduce_max_k<<<kH, 256, 0, stream>>>(f2, fmax);
  attn_mfma_k<<<dim3(64, kH, 4), 256, 0, stream>>>(Ht, f1, f2, fmax, packed, pacc);
  combine_k<<<dim3(64, kH), 256, 0, stream>>>(pacc, hcat, kHD);
  out_transform_k<<<kN, 64, 0, stream>>>(hcat, m2_Wout, m2_ao1, m2_ao2, Hto, fo1, fo2);
  reduce_max_k<<<1, 256, 0, stream>>>(fo2, fmax + 4);
  attn_mfma_k<<<dim3(64, 1, 4), 256, 0, stream>>>(Hto, fo1, fo2, fmax + 4, packed, pacc);
  combine_k<<<dim3(64, 1), 256, 0, stream>>>(pacc, g, kDim);
  final_k<<<kN, 64, 0, stream>>>(g, g2_W, g2_b, u, hx, out);
}

// Round 3
// 363.113 us; speedup vs baseline: 14.7742x; 1.5472x over previous
//
#include <hip/hip_runtime.h>
#include <hip/hip_bf16.h>

constexpr int kN = 4096;
constexpr int kDim = 66;   // U + IN
constexpr int kH = 4;
constexpr int kU = 64;
constexpr float kAlpha = 0.2f;
constexpr float kSlope = 0.01f;

typedef __attribute__((ext_vector_type(8))) short short8;
typedef __attribute__((ext_vector_type(4))) float floatx4;

__device__ inline unsigned short f2bf(float x){ // RNE, for epilogues / B-build
  unsigned int u = __float_as_uint(x);
  unsigned int r = (u + 0x7FFFu + ((u >> 16) & 1u)) >> 16;
  return (unsigned short)r;
}

// ---------- adjacency bit-pack: 67 MB int32 -> 2 MB bitmask ----------
__global__ void pack_adj_k(const int* __restrict__ adj, unsigned long long* __restrict__ packed){
  int gid = blockIdx.x * 256 + threadIdx.x;
  unsigned long long m = __ballot(adj[gid] != 0);
  if ((threadIdx.x & 63) == 0) packed[gid >> 6] = m;
}

// ---------- x1b = bf16 concat(inputs, hx) [4096][96]; x2b cols 0,1 = xi ----------
__global__ void prep_x_k(const float* __restrict__ in2, const float* __restrict__ hx,
                         unsigned short* __restrict__ x1b, unsigned short* __restrict__ x2b){
  int i = blockIdx.x * 4 + (threadIdx.x >> 6);
  int c = threadIdx.x & 63;
  x1b[(size_t)i * 96 + 2 + c] = f2bf(hx[(size_t)i * kU + c]);
  if (c < 2){
    unsigned short xv = f2bf(in2[i * 2 + c]);
    x1b[(size_t)i * 96 + c] = xv;
    x2b[(size_t)i * 96 + c] = xv;
  }
}

// ---------- build all transposed bf16 B matrices (n-major) ----------
__global__ void bbuild_k(const float* __restrict__ m1W, const float* __restrict__ m1a1, const float* __restrict__ m1a2,
                         const float* __restrict__ m1Wo, const float* __restrict__ m1ao1, const float* __restrict__ m1ao2,
                         const float* __restrict__ m2W, const float* __restrict__ m2a1, const float* __restrict__ m2a2,
                         const float* __restrict__ m2Wo, const float* __restrict__ m2ao1, const float* __restrict__ m2ao2,
                         const float* __restrict__ g1W, const float* __restrict__ g1b,
                         const float* __restrict__ g2W, const float* __restrict__ g2b,
                         unsigned short* __restrict__ B1t, unsigned short* __restrict__ B1t2,
                         unsigned short* __restrict__ B2t, unsigned short* __restrict__ B2t2,
                         unsigned short* __restrict__ Bgt, unsigned short* __restrict__ Bft){
  int b = blockIdx.x, t = threadIdx.x;
  if (b < 8){
    int m = b & 3;
    const float* W  = (b < 4 ? m1W  : m2W)  + (size_t)m * kDim * kDim;
    const float* a1 = (b < 4 ? m1a1 : m2a1) + m * kDim;
    const float* a2 = (b < 4 ? m1a2 : m2a2) + m * kDim;
    unsigned short* Bo = (b < 4 ? B1t : B1t2) + (size_t)m * 80 * 96;
    __shared__ float Ws[kDim * kDim];
    __shared__ float wa1s[kDim], wa2s[kDim];
    for (int z = t; z < kDim * kDim; z += 256) Ws[z] = W[z];
    __syncthreads();
    if (t < kDim){
      float s1 = 0.f, s2 = 0.f;
      for (int d = 0; d < kDim; d++){ float wv = Ws[t * kDim + d]; s1 += wv * a1[d]; s2 += wv * a2[d]; }
      wa1s[t] = s1; wa2s[t] = s2;
    }
    __syncthreads();
    for (int z = t; z < 80 * 96; z += 256){
      int nn = z / 96, k = z % 96;
      float val = 0.f;
      if (k < kDim){
        if (nn < kDim) val = Ws[k * kDim + nn];
        else if (nn == 66) val = wa1s[k];
        else if (nn == 67) val = wa2s[k];
      }
      Bo[z] = f2bf(val);
    }
  } else if (b < 10){
    const float* Wo  = (b == 8 ? m1Wo  : m2Wo);
    const float* ao1 = (b == 8 ? m1ao1 : m2ao1);
    const float* ao2 = (b == 8 ? m1ao2 : m2ao2);
    unsigned short* Bo = (b == 8 ? B2t : B2t2);
    __shared__ float wo1s[264], wo2s[264];
    for (int k = t; k < 264; k += 256){
      float s1 = 0.f, s2 = 0.f;
      for (int d = 0; d < kDim; d++){ float wv = Wo[(size_t)k * kDim + d]; s1 += wv * ao1[d]; s2 += wv * ao2[d]; }
      wo1s[k] = s1; wo2s[k] = s2;
    }
    __syncthreads();
    for (int z = t; z < 80 * 288; z += 256){
      int nn = z / 288, k = z % 288;
      float val = 0.f;
      if (k < 264){
        if (nn < kDim) val = Wo[(size_t)k * kDim + nn];
        else if (nn == 66) val = wo1s[k];
        else if (nn == 67) val = wo2s[k];
      }
      Bo[z] = f2bf(val);
    }
  } else if (b == 10){
    for (int z = t; z < 128 * 96; z += 256){
      int nn = z / 96, k = z % 96;
      float val = 0.f;
      if (k < kDim) val = g1W[k * 128 + nn];
      else if (k == 66) val = g1b[nn];
      Bgt[z] = f2bf(val);
    }
  } else {
    for (int z = t; z < 64 * 96; z += 256){
      int nn = z / 96, k = z % 96;
      float val = 0.f;
      if (k < kDim) val = g2W[k * 64 + nn];
      else if (k == 66) val = g2b[nn];
      Bft[z] = f2bf(val);
    }
  }
}

// ---------- generic MFMA GEMM with fused epilogues ----------
template<int KSTEPS, int NT, int EPI>
__global__ __launch_bounds__(256) void gemm_k(
    const unsigned short* __restrict__ A, const unsigned short* __restrict__ Bt,
    void* __restrict__ p0, void* __restrict__ p1, void* __restrict__ p2,
    const float* __restrict__ aux)
{
  constexpr int KP = KSTEPS * 32;
  const int m = blockIdx.y;
  const int i0 = blockIdx.x * 64;
  const int t = threadIdx.x;
  const int w = t >> 6, lane = t & 63, q = lane >> 4, n = lane & 15;
  const int arow = i0 + w * 16 + n;
  const unsigned short* Ar = A + (size_t)arow * KP;
  const unsigned short* Bm = Bt + (size_t)m * (NT * 16) * KP;
  floatx4 acc[NT];
  #pragma unroll
  for (int v = 0; v < NT; v++) acc[v] = (floatx4){0.f, 0.f, 0.f, 0.f};
  #pragma unroll
  for (int ks = 0; ks < KSTEPS; ks++){
    short8 af = *(const short8*)&Ar[ks * 32 + q * 8];
    #pragma unroll
    for (int nt = 0; nt < NT; nt++){
      short8 bf = *(const short8*)&Bm[(size_t)(nt * 16 + n) * KP + ks * 32 + q * 8];
      acc[nt] = __builtin_amdgcn_mfma_f32_16x16x32_bf16(af, bf, acc[nt], 0, 0, 0);
    }
  }
  const int ib = i0 + w * 16 + q * 4; // D row base
  if constexpr (EPI == 0){
    unsigned short* Ht = (unsigned short*)p0 + (size_t)m * 80 * kN;
    float* f1 = (float*)p1 + (size_t)m * kN;
    float* f2 = (float*)p2 + (size_t)m * kN;
    #pragma unroll
    for (int nt = 0; nt < NT; nt++){
      int c = nt * 16 + n;
      if (c < kDim){
        uint2 pk;
        pk.x = ((unsigned)f2bf(acc[nt][1]) << 16) | f2bf(acc[nt][0]);
        pk.y = ((unsigned)f2bf(acc[nt][3]) << 16) | f2bf(acc[nt][2]);
        *(uint2*)&Ht[(size_t)c * kN + ib] = pk;
      } else if (c == 66){
        float4 fv; fv.x = acc[nt][0]; fv.y = acc[nt][1]; fv.z = acc[nt][2]; fv.w = acc[nt][3];
        *(float4*)&f1[ib] = fv;
        *(uint2*)&Ht[(size_t)66 * kN + ib] = make_uint2(0x3F803F80u, 0x3F803F80u);
      } else if (c == 67){
        float4 fv; fv.x = acc[nt][0]; fv.y = acc[nt][1]; fv.z = acc[nt][2]; fv.w = acc[nt][3];
        *(float4*)&f2[ib] = fv;
        *(uint2*)&Ht[(size_t)67 * kN + ib] = make_uint2(0u, 0u);
      } else {
        *(uint2*)&Ht[(size_t)c * kN + ib] = make_uint2(0u, 0u);
      }
    }
  } else if constexpr (EPI == 1){
    float* u = (float*)p0;
    unsigned short* x2b = (unsigned short*)p1;
    #pragma unroll
    for (int nt = 0; nt < NT; nt++){
      int c = nt * 16 + n;
      #pragma unroll
      for (int r = 0; r < 4; r++){
        float v = 1.f / (1.f + __expf(-acc[nt][r]));
        if (c < 64) x2b[(size_t)(ib + r) * 96 + 2 + c] = f2bf(v * aux[(size_t)(ib + r) * kU + c]);
        else        u[(size_t)(ib + r) * kU + (c - 64)] = v;
      }
    }
  } else {
    float* outp = (float*)p0;
    const float* u = (const float*)p1;
    #pragma unroll
    for (int nt = 0; nt < NT; nt++){
      int c = nt * 16 + n;
      #pragma unroll
      for (int r = 0; r < 4; r++){
        float cc = tanhf(acc[nt][r]);
        float uv = u[(size_t)(ib + r) * kU + c];
        outp[(size_t)(ib + r) * kU + c] = uv * aux[(size_t)(ib + r) * kU + c] + (1.f - uv) * cc;
      }
    }
  }
}

// ---------- max over f2 per array ----------
__global__ void reduce_max_k(const float* __restrict__ f2, float* __restrict__ fmax){
  int m = blockIdx.x;
  const float* p = f2 + (size_t)m * kN;
  float v = -1e30f;
  for (int j = threadIdx.x; j < kN; j += 256) v = fmaxf(v, p[j]);
  #pragma unroll
  for (int o = 32; o; o >>= 1) v = fmaxf(v, __shfl_down(v, o));
  __shared__ float s[4];
  if ((threadIdx.x & 63) == 0) s[threadIdx.x >> 6] = v;
  __syncthreads();
  if (threadIdx.x == 0) fmax[m] = fmaxf(fmaxf(s[0], s[1]), fmaxf(s[2], s[3]));
}

// ---------- MFMA attention ----------
__global__ __launch_bounds__(256, 4) void attn_mfma_k(
    const unsigned short* __restrict__ Ht, const float* __restrict__ f1,
    const float* __restrict__ f2, const float* __restrict__ fmax,
    const unsigned long long* __restrict__ packed,
    float* __restrict__ pacc)
{
  const int m = blockIdx.y, js = blockIdx.z;
  const int i0 = blockIdx.x * 64;
  const int t = threadIdx.x;
  const int w = t >> 6, lane = t & 63, q = lane >> 4, n = lane & 15;
  const int i = i0 + w * 16 + n;
  const unsigned short* Hg = Ht + (size_t)m * 80 * kN;
  const float* f2m = f2 + (size_t)m * kN;
  const float f1v = f1[(size_t)m * kN + i];
  const float t0 = f1v + fmax[m];
  const float S = fmaxf(t0, kAlpha * t0);

  __shared__ __align__(16) unsigned short HtL[80 * 136];
  __shared__ __align__(16) float f2s[128];

  floatx4 acc[5];
  #pragma unroll
  for (int v = 0; v < 5; v++) acc[v] = (floatx4){0.f, 0.f, 0.f, 0.f};

  const int jbase = js * 1024;
  const unsigned long long* prow = packed + (size_t)i * 64;
  for (int ch = 0; ch < 8; ch++){
    const int j0 = jbase + ch * 128;
    __syncthreads();
    for (int z = t; z < 80 * 16; z += 256){
      int row = z >> 4, c16 = z & 15;
      *(uint4*)&HtL[row * 136 + c16 * 8] = *(const uint4*)&Hg[(size_t)row * kN + j0 + c16 * 8];
    }
    if (t < 128) f2s[t] = f2m[j0 + t];
    __syncthreads();
    unsigned long long w0 = prow[(j0 >> 6)];
    unsigned long long w1 = prow[(j0 >> 6) + 1];
    #pragma unroll
    for (int ks = 0; ks < 4; ks++){
      unsigned long long wsel = (ks < 2) ? w0 : w1;
      unsigned int bits = (unsigned int)((wsel >> ((ks & 1) * 32 + q * 8)) & 0xffull);
      float4 fa = *(const float4*)&f2s[ks * 32 + q * 8];
      float4 fb = *(const float4*)&f2s[ks * 32 + q * 8 + 4];
      float fv[8] = {fa.x, fa.y, fa.z, fa.w, fb.x, fb.y, fb.z, fb.w};
      float p[8];
      #pragma unroll
      for (int e = 0; e < 8; e++){
        float tt = f1v + fv[e];
        float ee = fmaxf(tt, kAlpha * tt);
        float pv = __expf(ee - S);
        p[e] = ((bits >> e) & 1u) ? pv : 0.f;
      }
      union { short8 s; unsigned int u[4]; } af;
      #pragma unroll
      for (int e2 = 0; e2 < 4; e2++)
        af.u[e2] = __builtin_amdgcn_perm(__float_as_uint(p[2 * e2 + 1]), __float_as_uint(p[2 * e2]), 0x07060302u);
      #pragma unroll
      for (int nt = 0; nt < 5; nt++){
        const short8 bf = *(const short8*)&HtL[(nt * 16 + n) * 136 + ks * 32 + q * 8];
        acc[nt] = __builtin_amdgcn_mfma_f32_16x16x32_bf16(af.s, bf, acc[nt], 0, 0, 0);
      }
    }
  }
  float* pw = pacc + ((size_t)(m * 4 + js) * kN + (i0 + w * 16)) * 80;
  #pragma unroll
  for (int nt = 0; nt < 5; nt++){
    #pragma unroll
    for (int r = 0; r < 4; r++)
      pw[(q * 4 + r) * 80 + nt * 16 + n] = acc[nt][r];
  }
}

// ---------- combine j-split partials -> lrelu -> bf16 ----------
__global__ void combine_k(const float* __restrict__ pacc, unsigned short* __restrict__ outb,
                          int ostride, int ones_col){
  int m = blockIdx.y;
  int i = blockIdx.x * 64 + (threadIdx.x >> 2);
  int cg = threadIdx.x & 3;
  const float* p0 = pacc + ((size_t)(m * 4) * kN + i) * 80;
  const float* p1 = p0 + (size_t)kN * 80;
  const float* p2 = p1 + (size_t)kN * 80;
  const float* p3 = p2 + (size_t)kN * 80;
  float l = p0[66] + p1[66] + p2[66] + p3[66];
  float inv = 1.f / l;
  unsigned short* orow = outb + (size_t)i * ostride + m * kDim;
  #pragma unroll
  for (int cc = 0; cc < 17; cc++){
    int c = cg * 17 + cc;
    if (c < kDim){
      float v = (p0[c] + p1[c] + p2[c] + p3[c]) * inv;
      v = fmaxf(v, kSlope * v);
      orow[c] = f2bf(v);
    }
  }
  if (ones_col && cg == 3) orow[66] = 0x3F80;
}

extern "C" void kernel_launch(void* const* d_in, const int* in_sizes, int n_in,
                              void* d_out, int out_size, void* d_ws, size_t ws_size,
                              hipStream_t stream){
  const float* inputs  = (const float*)d_in[0];
  const float* hx      = (const float*)d_in[1];
  const int*   adj     = (const int*)d_in[2];
  const float* m1_W    = (const float*)d_in[3];
  const float* m1_a1   = (const float*)d_in[4];
  const float* m1_a2   = (const float*)d_in[5];
  const float* m1_Wout = (const float*)d_in[6];
  const float* m1_ao1  = (const float*)d_in[7];
  const float* m1_ao2  = (const float*)d_in[8];
  const float* m2_W    = (const float*)d_in[9];
  const float* m2_a1   = (const float*)d_in[10];
  const float* m2_a2   = (const float*)d_in[11];
  const float* m2_Wout = (const float*)d_in[12];
  const float* m2_ao1  = (const float*)d_in[13];
  const float* m2_ao2  = (const float*)d_in[14];
  const float* g1_W    = (const float*)d_in[15];
  const float* g1_b    = (const float*)d_in[16];
  const float* g2_W    = (const float*)d_in[17];
  const float* g2_b    = (const float*)d_in[18];
  float* out = (float*)d_out;

  char* ws = (char*)d_ws;
  size_t off = 0;
  auto alloc = [&](size_t bytes) -> void* {
    void* p = ws + off;
    off = (off + bytes + 255) & ~(size_t)255;
    return p;
  };
  unsigned long long* packed = (unsigned long long*)alloc((size_t)kN * 64 * 8);
  unsigned short* x1b  = (unsigned short*)alloc((size_t)kN * 96 * 2);
  unsigned short* x2b  = (unsigned short*)alloc((size_t)kN * 96 * 2);
  unsigned short* Ht   = (unsigned short*)alloc((size_t)kH * 80 * kN * 2);
  unsigned short* Hto  = (unsigned short*)alloc((size_t)80 * kN * 2);
  unsigned short* hcatb= (unsigned short*)alloc((size_t)kN * 288 * 2);
  unsigned short* gb   = (unsigned short*)alloc((size_t)kN * 96 * 2);
  unsigned short* g2b  = (unsigned short*)alloc((size_t)kN * 96 * 2);
  float* f1   = (float*)alloc((size_t)kH * kN * 4);
  float* f2   = (float*)alloc((size_t)kH * kN * 4);
  float* fo1  = (float*)alloc((size_t)kN * 4);
  float* fo2  = (float*)alloc((size_t)kN * 4);
  float* fmax = (float*)alloc(64);
  float* u    = (float*)alloc((size_t)kN * kU * 4);
  float* pacc = (float*)alloc((size_t)16 * kN * 80 * 4);
  unsigned short* B1t  = (unsigned short*)alloc((size_t)kH * 80 * 96 * 2);
  unsigned short* B1t2 = (unsigned short*)alloc((size_t)kH * 80 * 96 * 2);
  unsigned short* B2t  = (unsigned short*)alloc((size_t)80 * 288 * 2);
  unsigned short* B2t2 = (unsigned short*)alloc((size_t)80 * 288 * 2);
  unsigned short* Bgt  = (unsigned short*)alloc((size_t)128 * 96 * 2);
  unsigned short* Bft  = (unsigned short*)alloc((size_t)64 * 96 * 2);
  (void)ws_size; (void)in_sizes; (void)n_in; (void)out_size;

  pack_adj_k<<<kN * kN / 256, 256, 0, stream>>>(adj, packed);
  prep_x_k<<<kN / 4, 256, 0, stream>>>(inputs, hx, x1b, x2b);
  bbuild_k<<<12, 256, 0, stream>>>(m1_W, m1_a1, m1_a2, m1_Wout, m1_ao1, m1_ao2,
                                   m2_W, m2_a1, m2_a2, m2_Wout, m2_ao1, m2_ao2,
                                   g1_W, g1_b, g2_W, g2_b,
                                   B1t, B1t2, B2t, B2t2, Bgt, Bft);

  // ---- subnet 1 ----
  gemm_k<3, 5, 0><<<dim3(64, kH), 256, 0, stream>>>(x1b, B1t, Ht, f1, f2, nullptr);
  reduce_max_k<<<kH, 256, 0, stream>>>(f2, fmax);
  attn_mfma_k<<<dim3(64, kH, 4), 256, 0, stream>>>(Ht, f1, f2, fmax, packed, pacc);
  combine_k<<<dim3(64, kH), 256, 0, stream>>>(pacc, hcatb, 288, 0);
  gemm_k<9, 5, 0><<<dim3(64, 1), 256, 0, stream>>>(hcatb, B2t, Hto, fo1, fo2, nullptr);
  reduce_max_k<<<1, 256, 0, stream>>>(fo2, fmax + 4);
  attn_mfma_k<<<dim3(64, 1, 4), 256, 0, stream>>>(Hto, fo1, fo2, fmax + 4, packed, pacc);
  combine_k<<<dim3(64, 1), 256, 0, stream>>>(pacc, gb, 96, 1);
  gemm_k<3, 8, 1><<<dim3(64, 1), 256, 0, stream>>>(gb, Bgt, u, x2b, nullptr, hx);

  // ---- subnet 2 ----
  gemm_k<3, 5, 0><<<dim3(64, kH), 256, 0, stream>>>(x2b, B1t2, Ht, f1, f2, nullptr);
  reduce_max_k<<<kH, 256, 0, stream>>>(f2, fmax);
  attn_mfma_k<<<dim3(64, kH, 4), 256, 0, stream>>>(Ht, f1, f2, fmax, packed, pacc);
  combine_k<<<dim3(64, kH), 256, 0, stream>>>(pacc, hcatb, 288, 0);
  gemm_k<9, 5, 0><<<dim3(64, 1), 256, 0, stream>>>(hcatb, B2t2, Hto, fo1, fo2, nullptr);
  reduce_max_k<<<1, 256, 0, stream>>>(fo2, fmax + 4);
  attn_mfma_k<<<dim3(64, 1, 4), 256, 0, stream>>>(Hto, fo1, fo2, fmax + 4, packed, pacc);
  combine_k<<<dim3(64, 1), 256, 0, stream>>>(pacc, g2b, 96, 1);
  gemm_k<3, 4, 2><<<dim3(64, 1), 256, 0, stream>>>(g2b, Bft, out, u, nullptr, hx);
}

// Round 4
// 349.252 us; speedup vs baseline: 15.3605x; 1.0397x over previous
//
#include <hip/hip_runtime.h>
#include <hip/hip_bf16.h>

constexpr int kN = 4096;
constexpr int kDim = 66;   // U + IN
constexpr int kH = 4;
constexpr int kU = 64;
constexpr float kAlpha = 0.2f;
constexpr float kSlope = 0.01f;
constexpr float kLog2e = 1.44269504f;

typedef __attribute__((ext_vector_type(8))) short short8;
typedef __attribute__((ext_vector_type(4))) float floatx4;

__device__ inline unsigned short f2bf(float x){ // RNE
  unsigned int u = __float_as_uint(x);
  unsigned int r = (u + 0x7FFFu + ((u >> 16) & 1u)) >> 16;
  return (unsigned short)r;
}
__device__ inline float bf2f(unsigned short v){
  return __uint_as_float((unsigned int)v << 16);
}
__device__ inline unsigned int fkey(float f){ // monotone float->uint key for atomicMax
  unsigned int u = __float_as_uint(f);
  return (u & 0x80000000u) ? ~u : (u | 0x80000000u);
}
__device__ inline float funkey(unsigned int k){
  unsigned int u = (k & 0x80000000u) ? (k ^ 0x80000000u) : ~k;
  return __uint_as_float(u);
}

// ---------- merged setup: pack adjacency + build bf16 x1/x2 + all B matrices + fmax init ----------
__global__ void setup_k(const int* __restrict__ adj, unsigned long long* __restrict__ packed,
                        const float* __restrict__ in2, const float* __restrict__ hx,
                        unsigned short* __restrict__ x1b, unsigned short* __restrict__ x2b,
                        const float* __restrict__ m1W, const float* __restrict__ m1a1, const float* __restrict__ m1a2,
                        const float* __restrict__ m1Wo, const float* __restrict__ m1ao1, const float* __restrict__ m1ao2,
                        const float* __restrict__ m2W, const float* __restrict__ m2a1, const float* __restrict__ m2a2,
                        const float* __restrict__ m2Wo, const float* __restrict__ m2ao1, const float* __restrict__ m2ao2,
                        const float* __restrict__ g1W, const float* __restrict__ g1b,
                        const float* __restrict__ g2W, const float* __restrict__ g2b,
                        unsigned short* __restrict__ B1t, unsigned short* __restrict__ B1t2,
                        unsigned short* __restrict__ B2t, unsigned short* __restrict__ B2t2,
                        unsigned short* __restrict__ Bgt, unsigned short* __restrict__ Bft,
                        unsigned int* __restrict__ fmaxbuf){
  int bb = blockIdx.x, t = threadIdx.x;
  if (bb < 16384){
    int gid = bb * 256 + t;
    unsigned long long m = __ballot(adj[gid] != 0);
    if ((t & 63) == 0) packed[gid >> 6] = m;
    return;
  }
  if (bb < 16384 + 1024){
    int i = (bb - 16384) * 4 + (t >> 6);
    int c = t & 63;
    x1b[(size_t)i * 96 + 2 + c] = f2bf(hx[(size_t)i * kU + c]);
    if (c < 2){
      unsigned short xv = f2bf(in2[i * 2 + c]);
      x1b[(size_t)i * 96 + c] = xv;
      x2b[(size_t)i * 96 + c] = xv;
    }
    return;
  }
  int b = bb - (16384 + 1024);
  if (b < 8){
    int m = b & 3;
    const float* W  = (b < 4 ? m1W  : m2W)  + (size_t)m * kDim * kDim;
    const float* a1 = (b < 4 ? m1a1 : m2a1) + m * kDim;
    const float* a2 = (b < 4 ? m1a2 : m2a2) + m * kDim;
    unsigned short* Bo = (b < 4 ? B1t : B1t2) + (size_t)m * 80 * 96;
    __shared__ float Ws[kDim * kDim];
    __shared__ float wa1s[kDim], wa2s[kDim];
    for (int z = t; z < kDim * kDim; z += 256) Ws[z] = W[z];
    __syncthreads();
    if (t < kDim){
      float s1 = 0.f, s2 = 0.f;
      for (int d = 0; d < kDim; d++){ float wv = Ws[t * kDim + d]; s1 += wv * a1[d]; s2 += wv * a2[d]; }
      wa1s[t] = s1; wa2s[t] = s2;
    }
    __syncthreads();
    for (int z = t; z < 80 * 96; z += 256){
      int nn = z / 96, k = z % 96;
      float val = 0.f;
      if (k < kDim){
        if (nn < kDim) val = Ws[k * kDim + nn];
        else if (nn == 66) val = wa1s[k];
        else if (nn == 67) val = wa2s[k];
      }
      Bo[z] = f2bf(val);
    }
  } else if (b < 10){
    const float* Wo  = (b == 8 ? m1Wo  : m2Wo);
    const float* ao1 = (b == 8 ? m1ao1 : m2ao1);
    const float* ao2 = (b == 8 ? m1ao2 : m2ao2);
    unsigned short* Bo = (b == 8 ? B2t : B2t2);
    __shared__ float wo1s[264], wo2s[264];
    for (int k = t; k < 264; k += 256){
      float s1 = 0.f, s2 = 0.f;
      for (int d = 0; d < kDim; d++){ float wv = Wo[(size_t)k * kDim + d]; s1 += wv * ao1[d]; s2 += wv * ao2[d]; }
      wo1s[k] = s1; wo2s[k] = s2;
    }
    __syncthreads();
    for (int z = t; z < 80 * 288; z += 256){
      int nn = z / 288, k = z % 288;
      float val = 0.f;
      if (k < 264){
        if (nn < kDim) val = Wo[(size_t)k * kDim + nn];
        else if (nn == 66) val = wo1s[k];
        else if (nn == 67) val = wo2s[k];
      }
      Bo[z] = f2bf(val);
    }
  } else if (b == 10){
    for (int z = t; z < 128 * 96; z += 256){
      int nn = z / 96, k = z % 96;
      float val = 0.f;
      if (k < kDim) val = g1W[k * 128 + nn];
      else if (k == 66) val = g1b[nn];
      Bgt[z] = f2bf(val);
    }
  } else {
    if (t < 16) fmaxbuf[t] = 0u; // init max-key slots
    for (int z = t; z < 64 * 96; z += 256){
      int nn = z / 96, k = z % 96;
      float val = 0.f;
      if (k < kDim) val = g2W[k * 64 + nn];
      else if (k == 66) val = g2b[nn];
      Bft[z] = f2bf(val);
    }
  }
}

// ---------- generic MFMA GEMM with fused epilogues ----------
// EPI 0: -> Ht (bf16 transposed + ones/zero rows), f1,f2 (pre-scaled by log2e), fmax atomic
// EPI 1: gate -> u = sigmoid; x2b cols 2..65 = sigmoid*hx
// EPI 2: final -> out = u*hx + (1-u)*tanh(acc)
template<int KSTEPS, int NT, int EPI>
__global__ __launch_bounds__(256) void gemm_k(
    const unsigned short* __restrict__ A, const unsigned short* __restrict__ Bt,
    void* __restrict__ p0, void* __restrict__ p1, void* __restrict__ p2,
    const float* __restrict__ aux, unsigned int* __restrict__ fmaxp)
{
  constexpr int KP = KSTEPS * 32;
  const int m = blockIdx.y;
  const int i0 = blockIdx.x * 64;
  const int t = threadIdx.x;
  const int w = t >> 6, lane = t & 63, q = lane >> 4, n = lane & 15;
  const int arow = i0 + w * 16 + n;
  const unsigned short* Ar = A + (size_t)arow * KP;
  const unsigned short* Bm = Bt + (size_t)m * (NT * 16) * KP;
  floatx4 acc[NT];
  #pragma unroll
  for (int v = 0; v < NT; v++) acc[v] = (floatx4){0.f, 0.f, 0.f, 0.f};
  #pragma unroll
  for (int ks = 0; ks < KSTEPS; ks++){
    short8 af = *(const short8*)&Ar[ks * 32 + q * 8];
    #pragma unroll
    for (int nt = 0; nt < NT; nt++){
      short8 bf = *(const short8*)&Bm[(size_t)(nt * 16 + n) * KP + ks * 32 + q * 8];
      acc[nt] = __builtin_amdgcn_mfma_f32_16x16x32_bf16(af, bf, acc[nt], 0, 0, 0);
    }
  }
  const int ib = i0 + w * 16 + q * 4; // D row base
  if constexpr (EPI == 0){
    unsigned short* Ht = (unsigned short*)p0 + (size_t)m * 80 * kN;
    float* f1 = (float*)p1 + (size_t)m * kN;
    float* f2 = (float*)p2 + (size_t)m * kN;
    float lm = -3e38f;
    #pragma unroll
    for (int nt = 0; nt < NT; nt++){
      int c = nt * 16 + n;
      if (c < kDim){
        uint2 pk;
        pk.x = ((unsigned)f2bf(acc[nt][1]) << 16) | f2bf(acc[nt][0]);
        pk.y = ((unsigned)f2bf(acc[nt][3]) << 16) | f2bf(acc[nt][2]);
        *(uint2*)&Ht[(size_t)c * kN + ib] = pk;
      } else if (c == 66){
        float4 fv; fv.x = acc[nt][0] * kLog2e; fv.y = acc[nt][1] * kLog2e;
        fv.z = acc[nt][2] * kLog2e; fv.w = acc[nt][3] * kLog2e;
        *(float4*)&f1[ib] = fv;
        *(uint2*)&Ht[(size_t)66 * kN + ib] = make_uint2(0x3F803F80u, 0x3F803F80u);
      } else if (c == 67){
        float4 fv; fv.x = acc[nt][0] * kLog2e; fv.y = acc[nt][1] * kLog2e;
        fv.z = acc[nt][2] * kLog2e; fv.w = acc[nt][3] * kLog2e;
        *(float4*)&f2[ib] = fv;
        lm = fmaxf(fmaxf(fv.x, fv.y), fmaxf(fv.z, fv.w));
        *(uint2*)&Ht[(size_t)67 * kN + ib] = make_uint2(0u, 0u);
      } else {
        *(uint2*)&Ht[(size_t)c * kN + ib] = make_uint2(0u, 0u);
      }
    }
    lm = fmaxf(lm, __shfl_xor(lm, 16));
    lm = fmaxf(lm, __shfl_xor(lm, 32));
    if (lane == 3) atomicMax(&fmaxp[m], fkey(lm));
  } else if constexpr (EPI == 1){
    float* u = (float*)p0;
    unsigned short* x2b = (unsigned short*)p1;
    #pragma unroll
    for (int nt = 0; nt < NT; nt++){
      int c = nt * 16 + n;
      #pragma unroll
      for (int r = 0; r < 4; r++){
        float v = 1.f / (1.f + __expf(-acc[nt][r]));
        if (c < 64) x2b[(size_t)(ib + r) * 96 + 2 + c] = f2bf(v * aux[(size_t)(ib + r) * kU + c]);
        else        u[(size_t)(ib + r) * kU + (c - 64)] = v;
      }
    }
  } else {
    float* outp = (float*)p0;
    const float* u = (const float*)p1;
    #pragma unroll
    for (int nt = 0; nt < NT; nt++){
      int c = nt * 16 + n;
      #pragma unroll
      for (int r = 0; r < 4; r++){
        float cc = tanhf(acc[nt][r]);
        float uv = u[(size_t)(ib + r) * kU + c];
        outp[(size_t)(ib + r) * kU + c] = uv * aux[(size_t)(ib + r) * kU + c] + (1.f - uv) * cc;
      }
    }
  }
}

// ---------- MFMA attention: paccb[m,js][i][0..79] = sum_j p_ij * Ht[j][col] (col 66 = l_i) ----------
__global__ __launch_bounds__(256, 4) void attn_mfma_k(
    const unsigned short* __restrict__ Ht, const float* __restrict__ f1,
    const float* __restrict__ f2, const unsigned int* __restrict__ fmaxu,
    const unsigned long long* __restrict__ packed,
    unsigned short* __restrict__ paccb)
{
  const int m = blockIdx.y, js = blockIdx.z;
  const int i0 = blockIdx.x * 64;
  const int t = threadIdx.x;
  const int w = t >> 6, lane = t & 63, q = lane >> 4, n = lane & 15;
  const int i = i0 + w * 16 + n;
  const unsigned short* Hg = Ht + (size_t)m * 80 * kN;
  const float* f2m = f2 + (size_t)m * kN;
  const float f1v = f1[(size_t)m * kN + i];       // pre-scaled by log2e
  const float fmx = funkey(fmaxu[m]);
  const float t0 = f1v + fmx;
  const float S = fmaxf(t0, kAlpha * t0);          // >= row max of scaled e

  __shared__ __align__(16) unsigned short HtL[80 * 136]; // 128 + 8 pad
  __shared__ __align__(16) float f2s[128];

  floatx4 acc[5];
  #pragma unroll
  for (int v = 0; v < 5; v++) acc[v] = (floatx4){0.f, 0.f, 0.f, 0.f};

  const int jbase = js * 1024;
  const unsigned long long* prow = packed + (size_t)i * 64;
  for (int ch = 0; ch < 8; ch++){
    const int j0 = jbase + ch * 128;
    __syncthreads();
    for (int z = t; z < 80 * 16; z += 256){
      int row = z >> 4, c16 = z & 15;
      *(uint4*)&HtL[row * 136 + c16 * 8] = *(const uint4*)&Hg[(size_t)row * kN + j0 + c16 * 8];
    }
    if (t < 128) f2s[t] = f2m[j0 + t];
    __syncthreads();
    unsigned long long w0 = prow[(j0 >> 6)];
    unsigned long long w1 = prow[(j0 >> 6) + 1];
    #pragma unroll
    for (int ks = 0; ks < 4; ks++){
      unsigned long long wsel = (ks < 2) ? w0 : w1;
      unsigned int bits = (unsigned int)((wsel >> ((ks & 1) * 32 + q * 8)) & 0xffull);
      float4 fa = *(const float4*)&f2s[ks * 32 + q * 8];
      float4 fb = *(const float4*)&f2s[ks * 32 + q * 8 + 4];
      float fv[8] = {fa.x, fa.y, fa.z, fa.w, fb.x, fb.y, fb.z, fb.w};
      float p[8];
      #pragma unroll
      for (int e = 0; e < 8; e++){
        float tt = f1v + fv[e];
        float ee = fmaxf(tt, kAlpha * tt);
        float pv = __builtin_amdgcn_exp2f(ee - S);
        p[e] = ((bits >> e) & 1u) ? pv : 0.f;
      }
      union { short8 s; unsigned int u[4]; } af;
      #pragma unroll
      for (int e2 = 0; e2 < 4; e2++)
        af.u[e2] = __builtin_amdgcn_perm(__float_as_uint(p[2 * e2 + 1]), __float_as_uint(p[2 * e2]), 0x07060302u);
      #pragma unroll
      for (int nt = 0; nt < 5; nt++){
        const short8 bf = *(const short8*)&HtL[(nt * 16 + n) * 136 + ks * 32 + q * 8];
        acc[nt] = __builtin_amdgcn_mfma_f32_16x16x32_bf16(af.s, bf, acc[nt], 0, 0, 0);
      }
    }
  }
  unsigned short* pw = paccb + ((size_t)(m * 4 + js) * kN + (i0 + w * 16)) * 80;
  #pragma unroll
  for (int nt = 0; nt < 5; nt++){
    #pragma unroll
    for (int r = 0; r < 4; r++)
      pw[(q * 4 + r) * 80 + nt * 16 + n] = f2bf(acc[nt][r]);
  }
}

// ---------- combine j-split bf16 partials -> lrelu -> bf16 rows ----------
__global__ void combine_k(const unsigned short* __restrict__ paccb, unsigned short* __restrict__ outb,
                          int ostride, int ones_col){
  int m = blockIdx.y;
  int i = blockIdx.x * 64 + (threadIdx.x >> 2);
  int cg = threadIdx.x & 3;
  const unsigned short* p0 = paccb + ((size_t)(m * 4) * kN + i) * 80;
  const unsigned short* p1 = p0 + (size_t)kN * 80;
  const unsigned short* p2 = p1 + (size_t)kN * 80;
  const unsigned short* p3 = p2 + (size_t)kN * 80;
  float l = bf2f(p0[66]) + bf2f(p1[66]) + bf2f(p2[66]) + bf2f(p3[66]);
  float inv = 1.f / l;
  unsigned short* orow = outb + (size_t)i * ostride + m * kDim;
  #pragma unroll
  for (int cc = 0; cc < 17; cc++){
    int c = cg * 17 + cc;
    if (c < kDim){
      float v = (bf2f(p0[c]) + bf2f(p1[c]) + bf2f(p2[c]) + bf2f(p3[c])) * inv;
      v = fmaxf(v, kSlope * v);
      orow[c] = f2bf(v);
    }
  }
  if (ones_col && cg == 3) orow[66] = 0x3F80;
}

extern "C" void kernel_launch(void* const* d_in, const int* in_sizes, int n_in,
                              void* d_out, int out_size, void* d_ws, size_t ws_size,
                              hipStream_t stream){
  const float* inputs  = (const float*)d_in[0];
  const float* hx      = (const float*)d_in[1];
  const int*   adj     = (const int*)d_in[2];
  const float* m1_W    = (const float*)d_in[3];
  const float* m1_a1   = (const float*)d_in[4];
  const float* m1_a2   = (const float*)d_in[5];
  const float* m1_Wout = (const float*)d_in[6];
  const float* m1_ao1  = (const float*)d_in[7];
  const float* m1_ao2  = (const float*)d_in[8];
  const float* m2_W    = (const float*)d_in[9];
  const float* m2_a1   = (const float*)d_in[10];
  const float* m2_a2   = (const float*)d_in[11];
  const float* m2_Wout = (const float*)d_in[12];
  const float* m2_ao1  = (const float*)d_in[13];
  const float* m2_ao2  = (const float*)d_in[14];
  const float* g1_W    = (const float*)d_in[15];
  const float* g1_b    = (const float*)d_in[16];
  const float* g2_W    = (const float*)d_in[17];
  const float* g2_b    = (const float*)d_in[18];
  float* out = (float*)d_out;

  char* ws = (char*)d_ws;
  size_t off = 0;
  auto alloc = [&](size_t bytes) -> void* {
    void* p = ws + off;
    off = (off + bytes + 255) & ~(size_t)255;
    return p;
  };
  unsigned long long* packed = (unsigned long long*)alloc((size_t)kN * 64 * 8);
  unsigned short* x1b  = (unsigned short*)alloc((size_t)kN * 96 * 2);
  unsigned short* x2b  = (unsigned short*)alloc((size_t)kN * 96 * 2);
  unsigned short* Ht   = (unsigned short*)alloc((size_t)kH * 80 * kN * 2);
  unsigned short* Hto  = (unsigned short*)alloc((size_t)80 * kN * 2);
  unsigned short* hcatb= (unsigned short*)alloc((size_t)kN * 288 * 2);
  unsigned short* gb   = (unsigned short*)alloc((size_t)kN * 96 * 2);
  unsigned short* g2b  = (unsigned short*)alloc((size_t)kN * 96 * 2);
  float* f1   = (float*)alloc((size_t)kH * kN * 4);
  float* f2   = (float*)alloc((size_t)kH * kN * 4);
  float* fo1  = (float*)alloc((size_t)kN * 4);
  float* fo2  = (float*)alloc((size_t)kN * 4);
  unsigned int* fmaxbuf = (unsigned int*)alloc(64);
  float* u    = (float*)alloc((size_t)kN * kU * 4);
  unsigned short* paccb = (unsigned short*)alloc((size_t)16 * kN * 80 * 2);
  unsigned short* B1t  = (unsigned short*)alloc((size_t)kH * 80 * 96 * 2);
  unsigned short* B1t2 = (unsigned short*)alloc((size_t)kH * 80 * 96 * 2);
  unsigned short* B2t  = (unsigned short*)alloc((size_t)80 * 288 * 2);
  unsigned short* B2t2 = (unsigned short*)alloc((size_t)80 * 288 * 2);
  unsigned short* Bgt  = (unsigned short*)alloc((size_t)128 * 96 * 2);
  unsigned short* Bft  = (unsigned short*)alloc((size_t)64 * 96 * 2);
  (void)ws_size; (void)in_sizes; (void)n_in; (void)out_size;

  setup_k<<<16384 + 1024 + 12, 256, 0, stream>>>(adj, packed, inputs, hx, x1b, x2b,
      m1_W, m1_a1, m1_a2, m1_Wout, m1_ao1, m1_ao2,
      m2_W, m2_a1, m2_a2, m2_Wout, m2_ao1, m2_ao2,
      g1_W, g1_b, g2_W, g2_b,
      B1t, B1t2, B2t, B2t2, Bgt, Bft, fmaxbuf);

  // ---- subnet 1 ----
  gemm_k<3, 5, 0><<<dim3(64, kH), 256, 0, stream>>>(x1b, B1t, Ht, f1, f2, nullptr, fmaxbuf + 0);
  attn_mfma_k<<<dim3(64, kH, 4), 256, 0, stream>>>(Ht, f1, f2, fmaxbuf + 0, packed, paccb);
  combine_k<<<dim3(64, kH), 256, 0, stream>>>(paccb, hcatb, 288, 0);
  gemm_k<9, 5, 0><<<dim3(64, 1), 256, 0, stream>>>(hcatb, B2t, Hto, fo1, fo2, nullptr, fmaxbuf + 4);
  attn_mfma_k<<<dim3(64, 1, 4), 256, 0, stream>>>(Hto, fo1, fo2, fmaxbuf + 4, packed, paccb);
  combine_k<<<dim3(64, 1), 256, 0, stream>>>(paccb, gb, 96, 1);
  gemm_k<3, 8, 1><<<dim3(64, 1), 256, 0, stream>>>(gb, Bgt, u, x2b, nullptr, hx, nullptr);

  // ---- subnet 2 ----
  gemm_k<3, 5, 0><<<dim3(64, kH), 256, 0, stream>>>(x2b, B1t2, Ht, f1, f2, nullptr, fmaxbuf + 5);
  attn_mfma_k<<<dim3(64, kH, 4), 256, 0, stream>>>(Ht, f1, f2, fmaxbuf + 5, packed, paccb);
  combine_k<<<dim3(64, kH), 256, 0, stream>>>(paccb, hcatb, 288, 0);
  gemm_k<9, 5, 0><<<dim3(64, 1), 256, 0, stream>>>(hcatb, B2t2, Hto, fo1, fo2, nullptr, fmaxbuf + 9);
  attn_mfma_k<<<dim3(64, 1, 4), 256, 0, stream>>>(Hto, fo1, fo2, fmaxbuf + 9, packed, paccb);
  combine_k<<<dim3(64, 1), 256, 0, stream>>>(paccb, g2b, 96, 1);
  gemm_k<3, 4, 2><<<dim3(64, 1), 256, 0, stream>>>(g2b, Bft, out, u, nullptr, hx, nullptr);
}

// Round 5
// 321.282 us; speedup vs baseline: 16.6978x; 1.0871x over previous
//
#include <hip/hip_runtime.h>
#include <hip/hip_bf16.h>

constexpr int kN = 4096;
constexpr int kDim = 66;   // U + IN
constexpr int kH = 4;
constexpr int kU = 64;
constexpr float kAlpha = 0.2f;
constexpr float kSlope = 0.01f;
constexpr float kLog2e = 1.44269504f;

typedef _Float16 half8 __attribute__((ext_vector_type(8)));
typedef _Float16 half2t __attribute__((ext_vector_type(2)));
typedef __attribute__((ext_vector_type(4))) float floatx4;

__device__ inline unsigned int fkey(float f){ // monotone float->uint key for atomicMax
  unsigned int u = __float_as_uint(f);
  return (u & 0x80000000u) ? ~u : (u | 0x80000000u);
}
__device__ inline float funkey(unsigned int k){
  unsigned int u = (k & 0x80000000u) ? (k ^ 0x80000000u) : ~k;
  return __uint_as_float(u);
}

// ---------- merged setup: pack adjacency + build fp16 x1/x2 + all B matrices + fmax init ----------
__global__ void setup_k(const int* __restrict__ adj, unsigned long long* __restrict__ packed,
                        const float* __restrict__ in2, const float* __restrict__ hx,
                        _Float16* __restrict__ x1b, _Float16* __restrict__ x2b,
                        const float* __restrict__ m1W, const float* __restrict__ m1a1, const float* __restrict__ m1a2,
                        const float* __restrict__ m1Wo, const float* __restrict__ m1ao1, const float* __restrict__ m1ao2,
                        const float* __restrict__ m2W, const float* __restrict__ m2a1, const float* __restrict__ m2a2,
                        const float* __restrict__ m2Wo, const float* __restrict__ m2ao1, const float* __restrict__ m2ao2,
                        const float* __restrict__ g1W, const float* __restrict__ g1b,
                        const float* __restrict__ g2W, const float* __restrict__ g2b,
                        _Float16* __restrict__ B1t, _Float16* __restrict__ B1t2,
                        _Float16* __restrict__ B2t, _Float16* __restrict__ B2t2,
                        _Float16* __restrict__ Bgt, _Float16* __restrict__ Bft,
                        unsigned int* __restrict__ fmaxbuf){
  int bb = blockIdx.x, t = threadIdx.x;
  if (bb < 16384){
    int gid = bb * 256 + t;
    unsigned long long m = __ballot(adj[gid] != 0);
    if ((t & 63) == 0) packed[gid >> 6] = m;
    return;
  }
  if (bb < 16384 + 1024){
    int i = (bb - 16384) * 4 + (t >> 6);
    int c = t & 63;
    x1b[(size_t)i * 96 + 2 + c] = (_Float16)hx[(size_t)i * kU + c];
    if (c < 2){
      _Float16 xv = (_Float16)in2[i * 2 + c];
      x1b[(size_t)i * 96 + c] = xv;
      x2b[(size_t)i * 96 + c] = xv;
    }
    if (c < 30){ // zero pad cols 66..95 (harness poisons ws)
      x1b[(size_t)i * 96 + 66 + c] = (_Float16)0.f;
      x2b[(size_t)i * 96 + 66 + c] = (_Float16)0.f;
    }
    return;
  }
  int b = bb - (16384 + 1024);
  if (b < 8){
    int m = b & 3;
    const float* W  = (b < 4 ? m1W  : m2W)  + (size_t)m * kDim * kDim;
    const float* a1 = (b < 4 ? m1a1 : m2a1) + m * kDim;
    const float* a2 = (b < 4 ? m1a2 : m2a2) + m * kDim;
    _Float16* Bo = (b < 4 ? B1t : B1t2) + (size_t)m * 80 * 96;
    __shared__ float Ws[kDim * kDim];
    __shared__ float wa1s[kDim], wa2s[kDim];
    for (int z = t; z < kDim * kDim; z += 256) Ws[z] = W[z];
    __syncthreads();
    if (t < kDim){
      float s1 = 0.f, s2 = 0.f;
      for (int d = 0; d < kDim; d++){ float wv = Ws[t * kDim + d]; s1 += wv * a1[d]; s2 += wv * a2[d]; }
      wa1s[t] = s1; wa2s[t] = s2;
    }
    __syncthreads();
    for (int z = t; z < 80 * 96; z += 256){
      int nn = z / 96, k = z % 96;
      float val = 0.f;
      if (k < kDim){
        if (nn < kDim) val = Ws[k * kDim + nn];
        else if (nn == 66) val = wa1s[k];
        else if (nn == 67) val = wa2s[k];
      }
      Bo[z] = (_Float16)val;
    }
  } else if (b < 10){
    const float* Wo  = (b == 8 ? m1Wo  : m2Wo);
    const float* ao1 = (b == 8 ? m1ao1 : m2ao1);
    const float* ao2 = (b == 8 ? m1ao2 : m2ao2);
    _Float16* Bo = (b == 8 ? B2t : B2t2);
    __shared__ float wo1s[264], wo2s[264];
    for (int k = t; k < 264; k += 256){
      float s1 = 0.f, s2 = 0.f;
      for (int d = 0; d < kDim; d++){ float wv = Wo[(size_t)k * kDim + d]; s1 += wv * ao1[d]; s2 += wv * ao2[d]; }
      wo1s[k] = s1; wo2s[k] = s2;
    }
    __syncthreads();
    for (int z = t; z < 80 * 288; z += 256){
      int nn = z / 288, k = z % 288;
      float val = 0.f;
      if (k < 264){
        if (nn < kDim) val = Wo[(size_t)k * kDim + nn];
        else if (nn == 66) val = wo1s[k];
        else if (nn == 67) val = wo2s[k];
      }
      Bo[z] = (_Float16)val;
    }
  } else if (b == 10){
    for (int z = t; z < 128 * 96; z += 256){
      int nn = z / 96, k = z % 96;
      float val = 0.f;
      if (k < kDim) val = g1W[k * 128 + nn];
      else if (k == 66) val = g1b[nn];
      Bgt[z] = (_Float16)val;
    }
  } else {
    if (t < 16) fmaxbuf[t] = 0u; // init max-key slots
    for (int z = t; z < 64 * 96; z += 256){
      int nn = z / 96, k = z % 96;
      float val = 0.f;
      if (k < kDim) val = g2W[k * 64 + nn];
      else if (k == 66) val = g2b[nn];
      Bft[z] = (_Float16)val;
    }
  }
}

// ---------- generic MFMA GEMM (fp16) with fused epilogues ----------
// EPI 0: -> Ht (fp16 transposed rows 0..67, row66=ones), f1,f2 (xlog2e, fp32), fmax atomic
// EPI 1: gate -> u = sigmoid; x2b cols 2..65 = sigmoid*hx (fp16)
// EPI 2: final -> out = u*hx + (1-u)*tanh(acc)
template<int KSTEPS, int NT, int EPI>
__global__ __launch_bounds__(256) void gemm_k(
    const _Float16* __restrict__ A, const _Float16* __restrict__ Bt,
    void* __restrict__ p0, void* __restrict__ p1, void* __restrict__ p2,
    const float* __restrict__ aux, unsigned int* __restrict__ fmaxp)
{
  constexpr int KP = KSTEPS * 32;
  const int m = blockIdx.y;
  const int i0 = blockIdx.x * 64;
  const int t = threadIdx.x;
  const int w = t >> 6, lane = t & 63, q = lane >> 4, n = lane & 15;
  const int arow = i0 + w * 16 + n;
  const _Float16* Ar = A + (size_t)arow * KP;
  const _Float16* Bm = Bt + (size_t)m * (NT * 16) * KP;
  floatx4 acc[NT];
  #pragma unroll
  for (int v = 0; v < NT; v++) acc[v] = (floatx4){0.f, 0.f, 0.f, 0.f};
  #pragma unroll
  for (int ks = 0; ks < KSTEPS; ks++){
    half8 af = *(const half8*)&Ar[ks * 32 + q * 8];
    #pragma unroll
    for (int nt = 0; nt < NT; nt++){
      half8 bf = *(const half8*)&Bm[(size_t)(nt * 16 + n) * KP + ks * 32 + q * 8];
      acc[nt] = __builtin_amdgcn_mfma_f32_16x16x32_f16(af, bf, acc[nt], 0, 0, 0);
    }
  }
  const int ib = i0 + w * 16 + q * 4; // D row base
  if constexpr (EPI == 0){
    _Float16* Ht = (_Float16*)p0 + (size_t)m * 68 * kN;
    float* f1 = (float*)p1 + (size_t)m * kN;
    float* f2 = (float*)p2 + (size_t)m * kN;
    float lm = -3e38f;
    #pragma unroll
    for (int nt = 0; nt < NT; nt++){
      int c = nt * 16 + n;
      if (c < kDim){
        union { _Float16 h[4]; uint2 v; } pk;
        pk.h[0] = (_Float16)acc[nt][0]; pk.h[1] = (_Float16)acc[nt][1];
        pk.h[2] = (_Float16)acc[nt][2]; pk.h[3] = (_Float16)acc[nt][3];
        *(uint2*)&Ht[(size_t)c * kN + ib] = pk.v;
      } else if (c == 66){
        float4 fv; fv.x = acc[nt][0] * kLog2e; fv.y = acc[nt][1] * kLog2e;
        fv.z = acc[nt][2] * kLog2e; fv.w = acc[nt][3] * kLog2e;
        *(float4*)&f1[ib] = fv;
        *(uint2*)&Ht[(size_t)66 * kN + ib] = make_uint2(0x3C003C00u, 0x3C003C00u); // fp16 ones
      } else if (c == 67){
        float4 fv; fv.x = acc[nt][0] * kLog2e; fv.y = acc[nt][1] * kLog2e;
        fv.z = acc[nt][2] * kLog2e; fv.w = acc[nt][3] * kLog2e;
        *(float4*)&f2[ib] = fv;
        lm = fmaxf(fmaxf(fv.x, fv.y), fmaxf(fv.z, fv.w));
        *(uint2*)&Ht[(size_t)67 * kN + ib] = make_uint2(0u, 0u);
      } // c >= 68: no store
    }
    lm = fmaxf(lm, __shfl_xor(lm, 16));
    lm = fmaxf(lm, __shfl_xor(lm, 32));
    if (lane == 3) atomicMax(&fmaxp[m], fkey(lm));
  } else if constexpr (EPI == 1){
    float* u = (float*)p0;
    _Float16* x2b = (_Float16*)p1;
    #pragma unroll
    for (int nt = 0; nt < NT; nt++){
      int c = nt * 16 + n;
      #pragma unroll
      for (int r = 0; r < 4; r++){
        float v = 1.f / (1.f + __expf(-acc[nt][r]));
        if (c < 64) x2b[(size_t)(ib + r) * 96 + 2 + c] = (_Float16)(v * aux[(size_t)(ib + r) * kU + c]);
        else        u[(size_t)(ib + r) * kU + (c - 64)] = v;
      }
    }
  } else {
    float* outp = (float*)p0;
    const float* u = (const float*)p1;
    #pragma unroll
    for (int nt = 0; nt < NT; nt++){
      int c = nt * 16 + n;
      #pragma unroll
      for (int r = 0; r < 4; r++){
        float cc = tanhf(acc[nt][r]);
        float uv = u[(size_t)(ib + r) * kU + c];
        outp[(size_t)(ib + r) * kU + c] = uv * aux[(size_t)(ib + r) * kU + c] + (1.f - uv) * cc;
      }
    }
  }
}

// ---------- MFMA attention (fp16, factorized softmax weights) ----------
// p_ij = exp2(lrelu(f1+f2)-S) = max(A1*B1_j, A2*B2_j); col 66 of Ht = ones -> l_i
template<int JSPLIT>
__global__ __launch_bounds__(256, 4) void attn_mfma_k(
    const _Float16* __restrict__ Ht, const float* __restrict__ f1,
    const float* __restrict__ f2, const unsigned int* __restrict__ fmaxu,
    const unsigned long long* __restrict__ packed,
    _Float16* __restrict__ paccb)
{
  constexpr int JR = kN / JSPLIT;      // j-range per block
  constexpr int NCH = JR / 128;        // 128-j chunks
  const int m = blockIdx.y, js = blockIdx.z;
  const int i0 = blockIdx.x * 64;
  const int t = threadIdx.x;
  const int w = t >> 6, lane = t & 63, q = lane >> 4, n = lane & 15;
  const int i = i0 + w * 16 + n;
  const _Float16* Hg = Ht + (size_t)m * 68 * kN;
  const float* f2m = f2 + (size_t)m * kN;
  const float f1v = f1[(size_t)m * kN + i];   // pre-scaled by log2e
  const float fmx = funkey(fmaxu[m]);
  const float t0 = f1v + fmx;
  const float S = fmaxf(t0, kAlpha * t0);      // >= row max of scaled e
  const float A1f = __builtin_amdgcn_exp2f(t0 - S);
  const float A2f = __builtin_amdgcn_exp2f(kAlpha * t0 - S);
  const half2t a1p = { (_Float16)A1f, (_Float16)A1f };
  const half2t a2p = { (_Float16)A2f, (_Float16)A2f };

  __shared__ __align__(16) _Float16 HtL[80 * 136]; // rows 68..79 zeroed once
  __shared__ __align__(16) _Float16 B1h[128], B2h[128];

  for (int z = t; z < 12 * 136; z += 256) HtL[68 * 136 + z] = (_Float16)0.f;

  floatx4 acc[5];
  #pragma unroll
  for (int v = 0; v < 5; v++) acc[v] = (floatx4){0.f, 0.f, 0.f, 0.f};

  const int jbase = js * JR;
  const unsigned long long* prow = packed + (size_t)i * 64;
  for (int ch = 0; ch < NCH; ch++){
    const int j0 = jbase + ch * 128;
    __syncthreads();
    for (int z = t; z < 68 * 16; z += 256){
      int row = z >> 4, c16 = z & 15;
      *(uint4*)&HtL[row * 136 + c16 * 8] = *(const uint4*)&Hg[(size_t)row * kN + j0 + c16 * 8];
    }
    if (t < 128){
      float v = f2m[j0 + t] - fmx;
      B1h[t] = (_Float16)__builtin_amdgcn_exp2f(v);
      B2h[t] = (_Float16)__builtin_amdgcn_exp2f(kAlpha * v);
    }
    __syncthreads();
    unsigned long long w0 = prow[(j0 >> 6)];
    unsigned long long w1 = prow[(j0 >> 6) + 1];
    #pragma unroll
    for (int ks = 0; ks < 4; ks++){
      unsigned long long wsel = (ks < 2) ? w0 : w1;
      unsigned int bits = (unsigned int)((wsel >> ((ks & 1) * 32 + q * 8)) & 0xffull);
      union { uint4 v; unsigned int u[4]; } b1v, b2v;
      b1v.v = *(const uint4*)&B1h[ks * 32 + q * 8];
      b2v.v = *(const uint4*)&B2h[ks * 32 + q * 8];
      union { half8 s; unsigned int u[4]; } af;
      #pragma unroll
      for (int e = 0; e < 4; e++){
        half2t x1 = __builtin_bit_cast(half2t, b1v.u[e]);
        half2t x2 = __builtin_bit_cast(half2t, b2v.u[e]);
        half2t m1 = x1 * a1p;
        half2t m2 = x2 * a2p;
        half2t pm = __builtin_elementwise_max(m1, m2);
        unsigned int mm = (((bits >> (2 * e)) & 1u) ? 0x0000FFFFu : 0u)
                        | (((bits >> (2 * e + 1)) & 1u) ? 0xFFFF0000u : 0u);
        af.u[e] = __builtin_bit_cast(unsigned int, pm) & mm;
      }
      #pragma unroll
      for (int nt = 0; nt < 5; nt++){
        const half8 bf = *(const half8*)&HtL[(nt * 16 + n) * 136 + ks * 32 + q * 8];
        acc[nt] = __builtin_amdgcn_mfma_f32_16x16x32_f16(af.s, bf, acc[nt], 0, 0, 0);
      }
    }
  }
  _Float16* pw = paccb + ((size_t)(m * JSPLIT + js) * kN + (i0 + w * 16)) * 80;
  #pragma unroll
  for (int nt = 0; nt < 5; nt++){
    if (nt < 4 || n < 4){ // cols >= 68 are unused
      #pragma unroll
      for (int r = 0; r < 4; r++)
        pw[(q * 4 + r) * 80 + nt * 16 + n] = (_Float16)acc[nt][r];
    }
  }
}

// ---------- combine j-split fp16 partials -> lrelu -> fp16 rows ----------
template<int JSPLIT>
__global__ void combine_k(const _Float16* __restrict__ paccb, _Float16* __restrict__ outb,
                          int ostride, int ones_col){
  int m = blockIdx.y;
  int i = blockIdx.x * 64 + (threadIdx.x >> 2);
  int cg = threadIdx.x & 3;
  const _Float16* ps[JSPLIT];
  #pragma unroll
  for (int s = 0; s < JSPLIT; s++)
    ps[s] = paccb + ((size_t)(m * JSPLIT + s) * kN + i) * 80;
  float l = 0.f;
  #pragma unroll
  for (int s = 0; s < JSPLIT; s++) l += (float)ps[s][66];
  float inv = 1.f / l;
  _Float16* orow = outb + (size_t)i * ostride + m * kDim;
  #pragma unroll
  for (int cc = 0; cc < 17; cc++){
    int c = cg * 17 + cc;
    if (c < kDim){
      float v = 0.f;
      #pragma unroll
      for (int s = 0; s < JSPLIT; s++) v += (float)ps[s][c];
      v *= inv;
      v = fmaxf(v, kSlope * v);
      orow[c] = (_Float16)v;
    }
  }
  if (ones_col && cg == 3) orow[66] = (_Float16)1.f;
}

extern "C" void kernel_launch(void* const* d_in, const int* in_sizes, int n_in,
                              void* d_out, int out_size, void* d_ws, size_t ws_size,
                              hipStream_t stream){
  const float* inputs  = (const float*)d_in[0];
  const float* hx      = (const float*)d_in[1];
  const int*   adj     = (const int*)d_in[2];
  const float* m1_W    = (const float*)d_in[3];
  const float* m1_a1   = (const float*)d_in[4];
  const float* m1_a2   = (const float*)d_in[5];
  const float* m1_Wout = (const float*)d_in[6];
  const float* m1_ao1  = (const float*)d_in[7];
  const float* m1_ao2  = (const float*)d_in[8];
  const float* m2_W    = (const float*)d_in[9];
  const float* m2_a1   = (const float*)d_in[10];
  const float* m2_a2   = (const float*)d_in[11];
  const float* m2_Wout = (const float*)d_in[12];
  const float* m2_ao1  = (const float*)d_in[13];
  const float* m2_ao2  = (const float*)d_in[14];
  const float* g1_W    = (const float*)d_in[15];
  const float* g1_b    = (const float*)d_in[16];
  const float* g2_W    = (const float*)d_in[17];
  const float* g2_b    = (const float*)d_in[18];
  float* out = (float*)d_out;

  char* ws = (char*)d_ws;
  size_t off = 0;
  auto alloc = [&](size_t bytes) -> void* {
    void* p = ws + off;
    off = (off + bytes + 255) & ~(size_t)255;
    return p;
  };
  unsigned long long* packed = (unsigned long long*)alloc((size_t)kN * 64 * 8);
  _Float16* x1b  = (_Float16*)alloc((size_t)kN * 96 * 2);
  _Float16* x2b  = (_Float16*)alloc((size_t)kN * 96 * 2);
  _Float16* Ht   = (_Float16*)alloc((size_t)kH * 68 * kN * 2);
  _Float16* Hto  = (_Float16*)alloc((size_t)68 * kN * 2);
  _Float16* hcatb= (_Float16*)alloc((size_t)kN * 288 * 2);
  _Float16* gb   = (_Float16*)alloc((size_t)kN * 96 * 2);
  _Float16* g2bv = (_Float16*)alloc((size_t)kN * 96 * 2);
  float* f1   = (float*)alloc((size_t)kH * kN * 4);
  float* f2   = (float*)alloc((size_t)kH * kN * 4);
  float* fo1  = (float*)alloc((size_t)kN * 4);
  float* fo2  = (float*)alloc((size_t)kN * 4);
  unsigned int* fmaxbuf = (unsigned int*)alloc(64);
  float* u    = (float*)alloc((size_t)kN * kU * 4);
  _Float16* paccb = (_Float16*)alloc((size_t)16 * kN * 80 * 2);
  _Float16* B1t  = (_Float16*)alloc((size_t)kH * 80 * 96 * 2);
  _Float16* B1t2 = (_Float16*)alloc((size_t)kH * 80 * 96 * 2);
  _Float16* B2t  = (_Float16*)alloc((size_t)80 * 288 * 2);
  _Float16* B2t2 = (_Float16*)alloc((size_t)80 * 288 * 2);
  _Float16* Bgt  = (_Float16*)alloc((size_t)128 * 96 * 2);
  _Float16* Bft  = (_Float16*)alloc((size_t)64 * 96 * 2);
  (void)ws_size; (void)in_sizes; (void)n_in; (void)out_size;

  setup_k<<<16384 + 1024 + 12, 256, 0, stream>>>(adj, packed, inputs, hx, x1b, x2b,
      m1_W, m1_a1, m1_a2, m1_Wout, m1_ao1, m1_ao2,
      m2_W, m2_a1, m2_a2, m2_Wout, m2_ao1, m2_ao2,
      g1_W, g1_b, g2_W, g2_b,
      B1t, B1t2, B2t, B2t2, Bgt, Bft, fmaxbuf);

  // ---- subnet 1 ----
  gemm_k<3, 5, 0><<<dim3(64, kH), 256, 0, stream>>>(x1b, B1t, Ht, f1, f2, nullptr, fmaxbuf + 0);
  attn_mfma_k<4><<<dim3(64, kH, 4), 256, 0, stream>>>(Ht, f1, f2, fmaxbuf + 0, packed, paccb);
  combine_k<4><<<dim3(64, kH), 256, 0, stream>>>(paccb, hcatb, 288, 0);
  gemm_k<9, 5, 0><<<dim3(64, 1), 256, 0, stream>>>(hcatb, B2t, Hto, fo1, fo2, nullptr, fmaxbuf + 4);
  attn_mfma_k<8><<<dim3(64, 1, 8), 256, 0, stream>>>(Hto, fo1, fo2, fmaxbuf + 4, packed, paccb);
  combine_k<8><<<dim3(64, 1), 256, 0, stream>>>(paccb, gb, 96, 1);
  gemm_k<3, 8, 1><<<dim3(64, 1), 256, 0, stream>>>(gb, Bgt, u, x2b, nullptr, hx, nullptr);

  // ---- subnet 2 ----
  gemm_k<3, 5, 0><<<dim3(64, kH), 256, 0, stream>>>(x2b, B1t2, Ht, f1, f2, nullptr, fmaxbuf + 5);
  attn_mfma_k<4><<<dim3(64, kH, 4), 256, 0, stream>>>(Ht, f1, f2, fmaxbuf + 5, packed, paccb);
  combine_k<4><<<dim3(64, kH), 256, 0, stream>>>(paccb, hcatb, 288, 0);
  gemm_k<9, 5, 0><<<dim3(64, 1), 256, 0, stream>>>(hcatb, B2t2, Hto, fo1, fo2, nullptr, fmaxbuf + 9);
  attn_mfma_k<8><<<dim3(64, 1, 8), 256, 0, stream>>>(Hto, fo1, fo2, fmaxbuf + 9, packed, paccb);
  combine_k<8><<<dim3(64, 1), 256, 0, stream>>>(paccb, g2bv, 96, 1);
  gemm_k<3, 4, 2><<<dim3(64, 1), 256, 0, stream>>>(g2bv, Bft, out, u, nullptr, hx, nullptr);
}